// Round 1
// baseline (1156.892 us; speedup 1.0000x reference)
//
#include <hip/hip_runtime.h>

typedef short short8 __attribute__((ext_vector_type(8)));
typedef float floatx4 __attribute__((ext_vector_type(4)));

constexpr int N_TOT = 1048576;
constexpr int N0 = 262144;
constexpr int N1 = 393216;
constexpr int N2 = 393216;
constexpr int EMBED = 128;
constexpr int FEAT = 512;

#define BM 128
#define BK 64
#define LDT 72   // padded LDS row stride in bf16 elements (144 B = 36 dwords -> 2-way max aliasing)

__device__ __forceinline__ unsigned short f2bf(float f) {
    // round-to-nearest-even fp32 -> bf16 (inputs are finite, no NaN handling needed)
    unsigned int u = __float_as_uint(f);
    u += 0x7FFFu + ((u >> 16) & 1u);
    return (unsigned short)(u >> 16);
}

// Kernel 0 (tiny): Wt[n][k] = bf16(W0[k][n]); n<128, k<512. 128 KB into d_ws.
__global__ void wt_kernel(const float* __restrict__ W0, unsigned short* __restrict__ Wt) {
    int idx = blockIdx.x * 256 + threadIdx.x;   // 0..65535
    int n = idx >> 9;
    int k = idx & 511;
    Wt[idx] = f2bf(W0[k * EMBED + n]);
}

// Kernel 1: out[loc] = emb[node_ids[loc]] for loc in concat(loc1, loc2).
// 32 lanes per row (float4 x 32 = 512 B), 8 rows per 256-thread block.
__global__ void gather_kernel(const int* __restrict__ node_ids,
                              const int* __restrict__ loc1,
                              const int* __restrict__ loc2,
                              const float* __restrict__ emb,
                              float* __restrict__ out) {
    int tid = threadIdx.x;
    int row = blockIdx.x * 8 + (tid >> 5);      // < N1+N2 (grid exact)
    int c = tid & 31;
    int loc = (row < N1) ? loc1[row] : loc2[row - N1];
    int nid = node_ids[loc];
    const float4* src = (const float4*)(emb + (size_t)nid * EMBED);
    float4* dst = (float4*)(out + (size_t)loc * EMBED);
    dst[c] = src[c];
}

// Kernel 2: scatter-GEMM. out[loc0[m], :] = feat0[m, :] @ W0   (bf16 MFMA, fp32 acc)
// Block: 256 threads = 4 waves; 128x128 C tile; each wave owns a 64x64 quadrant.
__global__ __launch_bounds__(256, 2) void gemm_kernel(
        const float* __restrict__ A,            // feat0 [N0][512]
        const unsigned short* __restrict__ Wt,  // [128 n][512 k] bf16
        const int* __restrict__ loc0,
        float* __restrict__ out) {

    __shared__ __align__(16) unsigned short As[BM * LDT];
    __shared__ __align__(16) unsigned short Bs[EMBED * LDT];
    __shared__ int s_loc[BM];

    int tid = threadIdx.x;
    int m0 = blockIdx.x * BM;

    if (tid < BM) s_loc[tid] = loc0[m0 + tid];

    floatx4 acc[4][4] = {};

    int w = tid >> 6;
    int lane = tid & 63;
    int lm = lane & 15;           // row/col within 16
    int q = lane >> 4;            // quad 0..3
    int wm = (w >> 1) * 64;
    int wn = (w & 1) * 64;

    int ar = tid >> 4;            // A-stage row base 0..15
    int ac = (tid & 15) * 4;      // A-stage col 0..60

    for (int kt = 0; kt < 8; ++kt) {
        // ---- stage A: 128x64 fp32 -> bf16 LDS (row-major, padded) ----
        #pragma unroll
        for (int i = 0; i < 8; ++i) {
            int r = ar + 16 * i;
            float4 v = *(const float4*)(A + (size_t)(m0 + r) * FEAT + kt * BK + ac);
            ushort4 b;
            b.x = f2bf(v.x); b.y = f2bf(v.y); b.z = f2bf(v.z); b.w = f2bf(v.w);
            *(ushort4*)&As[r * LDT + ac] = b;
        }
        // ---- stage B: 128x64 bf16 straight copy from Wt (n-major) ----
        #pragma unroll
        for (int i = 0; i < 4; ++i) {
            int flat = tid + i * 256;          // 0..1023 chunks of 8 bf16
            int n = flat >> 3;
            int k8 = (flat & 7) * 8;
            short8 v = *(const short8*)&Wt[n * FEAT + kt * BK + k8];
            *(short8*)&Bs[n * LDT + k8] = v;
        }
        __syncthreads();

        // ---- MFMA: 2 k-steps of 32, 4x4 16x16 tiles per wave ----
        #pragma unroll
        for (int ks = 0; ks < 2; ++ks) {
            short8 af[4], bf[4];
            #pragma unroll
            for (int t = 0; t < 4; ++t)
                af[t] = *(const short8*)&As[(wm + t * 16 + lm) * LDT + ks * 32 + q * 8];
            #pragma unroll
            for (int t = 0; t < 4; ++t)
                bf[t] = *(const short8*)&Bs[(wn + t * 16 + lm) * LDT + ks * 32 + q * 8];
            #pragma unroll
            for (int mt = 0; mt < 4; ++mt)
                #pragma unroll
                for (int nt = 0; nt < 4; ++nt)
                    acc[mt][nt] = __builtin_amdgcn_mfma_f32_16x16x32_bf16(
                        af[mt], bf[nt], acc[mt][nt], 0, 0, 0);
        }
        __syncthreads();
    }

    // ---- epilogue: C/D layout col=lane&15, row=q*4+reg; scatter rows via loc0 ----
    #pragma unroll
    for (int mt = 0; mt < 4; ++mt) {
        #pragma unroll
        for (int r = 0; r < 4; ++r) {
            int orow = s_loc[wm + mt * 16 + q * 4 + r];
            float* dst = out + (size_t)orow * EMBED + wn + lm;
            #pragma unroll
            for (int nt = 0; nt < 4; ++nt)
                dst[nt * 16] = acc[mt][nt][r];
        }
    }
}

extern "C" void kernel_launch(void* const* d_in, const int* in_sizes, int n_in,
                              void* d_out, int out_size, void* d_ws, size_t ws_size,
                              hipStream_t stream) {
    const int*   node_ids = (const int*)d_in[0];
    const int*   loc0     = (const int*)d_in[1];
    const int*   loc1     = (const int*)d_in[2];
    const int*   loc2     = (const int*)d_in[3];
    const float* feat0    = (const float*)d_in[4];
    const float* W0       = (const float*)d_in[5];
    const float* emb      = (const float*)d_in[6];
    float* out = (float*)d_out;
    unsigned short* Wt = (unsigned short*)d_ws;   // 128*512*2 = 128 KB

    wt_kernel<<<256, 256, 0, stream>>>(W0, Wt);
    gather_kernel<<<(N1 + N2) / 8, 256, 0, stream>>>(node_ids, loc1, loc2, emb, out);
    gemm_kernel<<<N0 / BM, 256, 0, stream>>>(feat0, Wt, loc0, out);
}